// Round 1
// baseline (1206.210 us; speedup 1.0000x reference)
//
#include <hip/hip_runtime.h>
#include <hip/hip_bf16.h>

typedef unsigned int u32;

#define NN 50000
#define EE 800000
#define GG 64
#define HH 3
#define CC 64
#define IN_DIM 75
#define HC 192           // H*C
#define TOTAL (EE + NN)  // edge entries incl self loops

// ---------------- helpers ----------------
__device__ __forceinline__ u32 fmap(float f) {
    u32 u = __float_as_uint(f);
    return (u & 0x80000000u) ? ~u : (u | 0x80000000u);
}
__device__ __forceinline__ float funmap(u32 m) {
    u32 u = (m & 0x80000000u) ? (m ^ 0x80000000u) : ~m;
    return __uint_as_float(u);
}

// ---------------- degree + edge-attr sum ----------------
__global__ void k_deg(const int* __restrict__ ei, const float* __restrict__ eattr,
                      int* __restrict__ deg, float* __restrict__ attrsum) {
    int e = blockIdx.x * 256 + threadIdx.x;
    if (e >= EE) return;
    int d = ei[EE + e];
    atomicAdd(&deg[d], 1);
    atomicAdd(&attrsum[d], eattr[e]);
}

// ---------------- prefix scan (deg+1) : 2-level ----------------
__global__ void k_scan1(const int* __restrict__ deg, u32* __restrict__ startv,
                        u32* __restrict__ blocksum) {
    __shared__ u32 sh[1024];
    int t = threadIdx.x;
    int n = blockIdx.x * 1024 + t;
    u32 v = (n < NN) ? (u32)(deg[n] + 1) : 0u;
    u32 val = v;
    sh[t] = val;
    __syncthreads();
    for (int off = 1; off < 1024; off <<= 1) {
        u32 y = (t >= off) ? sh[t - off] : 0u;
        __syncthreads();
        val += y;
        sh[t] = val;
        __syncthreads();
    }
    if (n < NN) startv[n] = val - v;   // block-exclusive
    if (t == 0) blocksum[blockIdx.x] = sh[1023];
}

__global__ void k_scan2(u32* __restrict__ blocksum, int nb) {
    if (threadIdx.x == 0) {
        u32 acc = 0;
        for (int b = 0; b < nb; b++) { u32 t = blocksum[b]; blocksum[b] = acc; acc += t; }
    }
}

__global__ void k_scan3(u32* __restrict__ startv, const u32* __restrict__ blocksum,
                        u32* __restrict__ cursor) {
    int n = blockIdx.x * 256 + threadIdx.x;
    if (n >= NN) return;
    u32 s = startv[n] + blocksum[n >> 10];
    startv[n] = s;
    cursor[n] = s;
}

__global__ void k_fill(const int* __restrict__ ei, u32* __restrict__ cursor,
                       u32* __restrict__ eid) {
    int i = blockIdx.x * 256 + threadIdx.x;
    if (i >= TOTAL) return;
    int d = (i < EE) ? ei[EE + i] : (i - EE);
    u32 pos = atomicAdd(&cursor[d], 1u);
    eid[pos] = (u32)i;
}

// ---------------- per-head scalar: dot(We_col_h, a_e_h) for both layers ----------------
__global__ void k_wedot(const float* __restrict__ We1, const float* __restrict__ ae1,
                        const float* __restrict__ We2, const float* __restrict__ ae2,
                        float* __restrict__ wedot) {
    int w = threadIdx.x >> 6;      // 0..5
    int c = threadIdx.x & 63;
    int layer = w / 3, h = w % 3;
    const float* We = layer ? We2 : We1;
    const float* ae = layer ? ae2 : ae1;
    float v = We[h * 64 + c] * ae[h * 64 + c];
#pragma unroll
    for (int off = 32; off; off >>= 1) v += __shfl_xor(v, off, 64);
    if (c == 0) wedot[layer * 3 + h] = v;
}

// ---------------- GEMM: out[N,192] = x[N,K] @ W[K,192] ----------------
template <int K>
__global__ void k_gemm(const float* __restrict__ x, const float* __restrict__ W,
                       float* __restrict__ out) {
    __shared__ float xs[32 * K];
    int n0 = blockIdx.x * 32;
    int tid = threadIdx.x;   // 0..191
    for (int t = tid; t < 32 * K; t += 192) {
        int i = t / K, k = t - i * K;
        int n = n0 + i;
        xs[t] = (n < NN) ? x[n * K + k] : 0.f;
    }
    __syncthreads();
    float acc[32];
#pragma unroll
    for (int i = 0; i < 32; i++) acc[i] = 0.f;
    int j = tid;
    for (int k = 0; k < K; k++) {
        float wk = W[k * HC + j];
#pragma unroll
        for (int i = 0; i < 32; i++) acc[i] += xs[i * K + k] * wk;
    }
    int rem = NN - n0;
#pragma unroll
    for (int i = 0; i < 32; i++)
        if (i < rem) out[(n0 + i) * HC + j] = acc[i];
}

// ---------------- per-node attention dots ----------------
__global__ void k_attdot(const float* __restrict__ xh, const float* __restrict__ asrcw,
                         const float* __restrict__ adstw, float* __restrict__ asrc,
                         float* __restrict__ adst) {
    int n = blockIdx.x;
    int h = threadIdx.x >> 6, c = threadIdx.x & 63;
    float v = xh[n * HC + h * 64 + c];
    float p = v * asrcw[h * 64 + c];
    float q = v * adstw[h * 64 + c];
#pragma unroll
    for (int off = 32; off; off >>= 1) {
        p += __shfl_xor(p, off, 64);
        q += __shfl_xor(q, off, 64);
    }
    if (c == 0) { asrc[n * 3 + h] = p; adst[n * 3 + h] = q; }
}

// ---------------- alpha (leaky relu) for all E+N entries ----------------
__global__ void k_alpha(const int* __restrict__ ei, const float* __restrict__ eattr,
                        const float* __restrict__ asrc, const float* __restrict__ adst,
                        const float* __restrict__ attrsum, const int* __restrict__ deg,
                        const float* __restrict__ wedot, int woff,
                        float* __restrict__ attn) {
    int i = blockIdx.x * 256 + threadIdx.x;
    if (i >= TOTAL) return;
    int s, d;
    float ea;
    if (i < EE) {
        s = ei[i]; d = ei[EE + i]; ea = eattr[i];
    } else {
        s = d = i - EE;
        ea = attrsum[s] / fmaxf((float)deg[s], 1.f);
    }
#pragma unroll
    for (int h = 0; h < 3; h++) {
        float a = asrc[s * 3 + h] + adst[d * 3 + h] + ea * wedot[woff + h];
        attn[i * 3 + h] = (a > 0.f) ? a : 0.2f * a;
    }
}

// ---------------- segment softmax (gather, per node, 1 wave) ----------------
__global__ void k_softmax(const u32* __restrict__ startv, const int* __restrict__ deg,
                          const u32* __restrict__ eid, float* __restrict__ attn) {
    int n = blockIdx.x;
    int lane = threadIdx.x;
    u32 st = startv[n];
    int L = deg[n] + 1;
    float m0 = -1e30f, m1 = -1e30f, m2 = -1e30f;
    for (int p = lane; p < L; p += 64) {
        u32 i = eid[st + p];
        m0 = fmaxf(m0, attn[i * 3 + 0]);
        m1 = fmaxf(m1, attn[i * 3 + 1]);
        m2 = fmaxf(m2, attn[i * 3 + 2]);
    }
#pragma unroll
    for (int off = 32; off; off >>= 1) {
        m0 = fmaxf(m0, __shfl_xor(m0, off, 64));
        m1 = fmaxf(m1, __shfl_xor(m1, off, 64));
        m2 = fmaxf(m2, __shfl_xor(m2, off, 64));
    }
    float s0 = 0.f, s1 = 0.f, s2 = 0.f;
    for (int p = lane; p < L; p += 64) {
        u32 i = eid[st + p];
        float e0 = __expf(attn[i * 3 + 0] - m0);
        float e1 = __expf(attn[i * 3 + 1] - m1);
        float e2 = __expf(attn[i * 3 + 2] - m2);
        attn[i * 3 + 0] = e0; attn[i * 3 + 1] = e1; attn[i * 3 + 2] = e2;
        s0 += e0; s1 += e1; s2 += e2;
    }
#pragma unroll
    for (int off = 32; off; off >>= 1) {
        s0 += __shfl_xor(s0, off, 64);
        s1 += __shfl_xor(s1, off, 64);
        s2 += __shfl_xor(s2, off, 64);
    }
    float r0 = 1.f / (s0 + 1e-16f), r1 = 1.f / (s1 + 1e-16f), r2 = 1.f / (s2 + 1e-16f);
    for (int p = lane; p < L; p += 64) {
        u32 i = eid[st + p];
        attn[i * 3 + 0] *= r0;
        attn[i * 3 + 1] *= r1;
        attn[i * 3 + 2] *= r2;
    }
}

// ---------------- aggregation gather + bias + elu ----------------
__global__ void k_gather(const u32* __restrict__ startv, const int* __restrict__ deg,
                         const u32* __restrict__ eid, const int* __restrict__ ei,
                         const float* __restrict__ attn, const float* __restrict__ xh,
                         const float* __restrict__ bias, float* __restrict__ hout) {
    int n = blockIdx.x;
    int j = threadIdx.x;      // 0..191
    int h = j >> 6;
    u32 st = startv[n];
    int L = deg[n] + 1;
    float acc = 0.f;
    for (int p = 0; p < L; p++) {
        u32 i = eid[st + p];
        int s = (i < (u32)EE) ? ei[i] : (int)(i - EE);
        float a = attn[i * 3 + h];
        acc += a * xh[s * HC + j];
    }
    float o = acc + bias[j];
    hout[n * HC + j] = (o > 0.f) ? o : expm1f(o);
}

// ---------------- pooling ----------------
__global__ void k_poolinit(u32* __restrict__ pmax) {
    int i = blockIdx.x * 256 + threadIdx.x;
    if (i < GG * HC) pmax[i] = 0x007FFFFFu;   // fmap(-inf)
}

__global__ void k_pool(const float* __restrict__ h2, const int* __restrict__ batch,
                       float* __restrict__ psum, u32* __restrict__ pmax,
                       int* __restrict__ pcnt) {
    const int CH = 256;
    int n0 = blockIdx.x * CH;
    if (n0 >= NN) return;
    int j = threadIdx.x;
    int nend = min(NN, n0 + CH);
    int curg = batch[n0];
    float sum = 0.f, mx = -1e30f;
    int c = 0;
    for (int n = n0; n < nend; n++) {
        int g = batch[n];
        if (g != curg) {
            atomicAdd(&psum[curg * HC + j], sum);
            atomicMax(&pmax[curg * HC + j], fmap(mx));
            if (j == 0) atomicAdd(&pcnt[curg], c);
            sum = 0.f; mx = -1e30f; c = 0; curg = g;
        }
        float v = h2[n * HC + j];
        sum += v;
        mx = fmaxf(mx, v);
        c++;
    }
    atomicAdd(&psum[curg * HC + j], sum);
    atomicMax(&pmax[curg * HC + j], fmap(mx));
    if (j == 0) atomicAdd(&pcnt[curg], c);
}

// ---------------- head MLP ----------------
__global__ void k_head(const float* __restrict__ psum, const u32* __restrict__ pmax,
                       const int* __restrict__ pcnt, const float* __restrict__ fc1w,
                       const float* __restrict__ fc1b, const float* __restrict__ fc2w,
                       const float* __restrict__ fc2b, float* __restrict__ logits) {
    __shared__ float z[2 * HC];
    int g = blockIdx.x;
    int t = threadIdx.x;   // 0..63
    float cnt = fmaxf((float)pcnt[g], 1.f);
    for (int k = t; k < 2 * HC; k += 64)
        z[k] = (k < HC) ? psum[g * HC + k] / cnt : funmap(pmax[g * HC + (k - HC)]);
    __syncthreads();
    float acc = fc1b[t];
    for (int k = 0; k < 2 * HC; k++) acc += z[k] * fc1w[k * 64 + t];
    acc = fmaxf(acc, 0.f);
    float v = acc * fc2w[t];
#pragma unroll
    for (int off = 32; off; off >>= 1) v += __shfl_xor(v, off, 64);
    if (t == 0) logits[g] = v + fc2b[0];
}

// ---------------- launcher ----------------
extern "C" void kernel_launch(void* const* d_in, const int* in_sizes, int n_in,
                              void* d_out, int out_size, void* d_ws, size_t ws_size,
                              hipStream_t stream) {
    const float* x     = (const float*)d_in[0];
    const float* eattr = (const float*)d_in[1];
    const float* W1    = (const float*)d_in[2];
    const float* as1   = (const float*)d_in[3];
    const float* ad1   = (const float*)d_in[4];
    const float* We1   = (const float*)d_in[5];
    const float* ae1   = (const float*)d_in[6];
    const float* b1    = (const float*)d_in[7];
    const float* W2    = (const float*)d_in[8];
    const float* as2   = (const float*)d_in[9];
    const float* ad2   = (const float*)d_in[10];
    const float* We2   = (const float*)d_in[11];
    const float* ae2   = (const float*)d_in[12];
    const float* b2    = (const float*)d_in[13];
    const float* fc1w  = (const float*)d_in[14];
    const float* fc1b  = (const float*)d_in[15];
    const float* fc2w  = (const float*)d_in[16];
    const float* fc2b  = (const float*)d_in[17];
    const int* ei      = (const int*)d_in[18];
    const int* batch   = (const int*)d_in[19];

    float* logits = (float*)d_out;
    float* attn1  = logits + GG;
    float* attn2  = attn1 + (size_t)TOTAL * 3;

    // workspace layout
    float* bufA    = (float*)d_ws;                 // N*192  (xh)
    float* bufB    = bufA + (size_t)NN * HC;       // N*192  (h)
    int*   deg     = (int*)(bufB + (size_t)NN * HC);
    float* attrsum = (float*)(deg + NN);
    float* asrc    = attrsum + NN;                 // N*3
    float* adst    = asrc + NN * 3;                // N*3
    u32*   startv  = (u32*)(adst + NN * 3);        // N
    u32*   cursor  = startv + NN;                  // N
    u32*   blocksum= cursor + NN;                  // 64
    float* wedot   = (float*)(blocksum + 64);      // 8
    float* psum    = wedot + 8;                    // G*192
    u32*   pmax    = (u32*)(psum + GG * HC);       // G*192
    int*   pcnt    = (int*)(pmax + GG * HC);       // G
    u32*   eid     = (u32*)(pcnt + 64);            // E+N

    // zero init
    hipMemsetAsync(deg, 0, NN * sizeof(int), stream);
    hipMemsetAsync(attrsum, 0, NN * sizeof(float), stream);
    hipMemsetAsync(psum, 0, GG * HC * sizeof(float), stream);
    hipMemsetAsync(pcnt, 0, GG * sizeof(int), stream);

    // graph structure (shared by both layers)
    k_deg<<<(EE + 255) / 256, 256, 0, stream>>>(ei, eattr, deg, attrsum);
    k_scan1<<<49, 1024, 0, stream>>>(deg, startv, blocksum);
    k_scan2<<<1, 64, 0, stream>>>(blocksum, 49);
    k_scan3<<<(NN + 255) / 256, 256, 0, stream>>>(startv, blocksum, cursor);
    k_fill<<<(TOTAL + 255) / 256, 256, 0, stream>>>(ei, cursor, eid);
    k_wedot<<<1, 384, 0, stream>>>(We1, ae1, We2, ae2, wedot);
    k_poolinit<<<(GG * HC + 255) / 256, 256, 0, stream>>>(pmax);

    const int NB = (NN + 31) / 32;

    // ---- layer 1 ----
    k_gemm<IN_DIM><<<NB, 192, 0, stream>>>(x, W1, bufA);
    k_attdot<<<NN, 192, 0, stream>>>(bufA, as1, ad1, asrc, adst);
    k_alpha<<<(TOTAL + 255) / 256, 256, 0, stream>>>(ei, eattr, asrc, adst, attrsum, deg,
                                                     wedot, 0, attn1);
    k_softmax<<<NN, 64, 0, stream>>>(startv, deg, eid, attn1);
    k_gather<<<NN, 192, 0, stream>>>(startv, deg, eid, ei, attn1, bufA, b1, bufB);

    // ---- layer 2 ----
    k_gemm<HC><<<NB, 192, 0, stream>>>(bufB, W2, bufA);
    k_attdot<<<NN, 192, 0, stream>>>(bufA, as2, ad2, asrc, adst);
    k_alpha<<<(TOTAL + 255) / 256, 256, 0, stream>>>(ei, eattr, asrc, adst, attrsum, deg,
                                                     wedot, 3, attn2);
    k_softmax<<<NN, 64, 0, stream>>>(startv, deg, eid, attn2);
    k_gather<<<NN, 192, 0, stream>>>(startv, deg, eid, ei, attn2, bufA, b2, bufB);

    // ---- pooling + head ----
    k_pool<<<(NN + 255) / 256, 192, 0, stream>>>(bufB, batch, psum, pmax, pcnt);
    k_head<<<GG, 64, 0, stream>>>(psum, pmax, pcnt, fc1w, fc1b, fc2w, fc2b, logits);
}

// Round 2
// 909.229 us; speedup vs baseline: 1.3266x; 1.3266x over previous
//
#include <hip/hip_runtime.h>
#include <hip/hip_bf16.h>

typedef unsigned int u32;

#define NN 50000
#define EE 800000
#define GG 64
#define HH 3
#define CC 64
#define IN_DIM 75
#define HC 192           // H*C
#define TOTAL (EE + NN)  // edge entries incl self loops

// ---------------- helpers ----------------
__device__ __forceinline__ u32 fmap(float f) {
    u32 u = __float_as_uint(f);
    return (u & 0x80000000u) ? ~u : (u | 0x80000000u);
}
__device__ __forceinline__ float funmap(u32 m) {
    u32 u = (m & 0x80000000u) ? (m ^ 0x80000000u) : ~m;
    return __uint_as_float(u);
}

// ---------------- degree + edge-attr sum ----------------
__global__ void k_deg(const int* __restrict__ ei, const float* __restrict__ eattr,
                      int* __restrict__ deg, float* __restrict__ attrsum) {
    int e = blockIdx.x * 256 + threadIdx.x;
    if (e >= EE) return;
    int d = ei[EE + e];
    atomicAdd(&deg[d], 1);
    atomicAdd(&attrsum[d], eattr[e]);
}

// ---------------- prefix scan (deg+1) : 2-level ----------------
__global__ void k_scan1(const int* __restrict__ deg, u32* __restrict__ startv,
                        u32* __restrict__ blocksum) {
    __shared__ u32 sh[1024];
    int t = threadIdx.x;
    int n = blockIdx.x * 1024 + t;
    u32 v = (n < NN) ? (u32)(deg[n] + 1) : 0u;
    u32 val = v;
    sh[t] = val;
    __syncthreads();
    for (int off = 1; off < 1024; off <<= 1) {
        u32 y = (t >= off) ? sh[t - off] : 0u;
        __syncthreads();
        val += y;
        sh[t] = val;
        __syncthreads();
    }
    if (n < NN) startv[n] = val - v;   // block-exclusive
    if (t == 0) blocksum[blockIdx.x] = sh[1023];
}

__global__ void k_scan2(u32* __restrict__ blocksum, int nb) {
    if (threadIdx.x == 0) {
        u32 acc = 0;
        for (int b = 0; b < nb; b++) { u32 t = blocksum[b]; blocksum[b] = acc; acc += t; }
    }
}

__global__ void k_scan3(u32* __restrict__ startv, const u32* __restrict__ blocksum,
                        u32* __restrict__ cursor) {
    int n = blockIdx.x * 256 + threadIdx.x;
    if (n >= NN) return;
    u32 s = startv[n] + blocksum[n >> 10];
    startv[n] = s;
    cursor[n] = s;
}

// fill CSR-ordered streams: srcP/dstP/eaP packed by destination segment; posOf maps entry->pos
__global__ void k_fill(const int* __restrict__ ei, const float* __restrict__ eattr,
                       const float* __restrict__ attrsum, const int* __restrict__ deg,
                       u32* __restrict__ cursor, int* __restrict__ srcP,
                       int* __restrict__ dstP, float* __restrict__ eaP,
                       u32* __restrict__ posOf) {
    int i = blockIdx.x * 256 + threadIdx.x;
    if (i >= TOTAL) return;
    int s, d;
    float ea;
    if (i < EE) {
        s = ei[i]; d = ei[EE + i]; ea = eattr[i];
    } else {
        s = d = i - EE;
        ea = attrsum[s] / fmaxf((float)deg[s], 1.f);
    }
    u32 pos = atomicAdd(&cursor[d], 1u);
    srcP[pos] = s;
    dstP[pos] = d;
    eaP[pos] = ea;
    posOf[i] = pos;
}

// ---------------- per-head scalar: dot(We_col_h, a_e_h) for both layers ----------------
__global__ void k_wedot(const float* __restrict__ We1, const float* __restrict__ ae1,
                        const float* __restrict__ We2, const float* __restrict__ ae2,
                        float* __restrict__ wedot) {
    int w = threadIdx.x >> 6;      // 0..5
    int c = threadIdx.x & 63;
    int layer = w / 3, h = w % 3;
    const float* We = layer ? We2 : We1;
    const float* ae = layer ? ae2 : ae1;
    float v = We[h * 64 + c] * ae[h * 64 + c];
#pragma unroll
    for (int off = 32; off; off >>= 1) v += __shfl_xor(v, off, 64);
    if (c == 0) wedot[layer * 3 + h] = v;
}

// ---------------- GEMM: out[N,192] = x[N,K] @ W[K,192], fused attdot epilogue ----------
template <int K>
__global__ void k_gemm(const float* __restrict__ x, const float* __restrict__ W,
                       const float* __restrict__ asrcw, const float* __restrict__ adstw,
                       float* __restrict__ out, float* __restrict__ asrc,
                       float* __restrict__ adst) {
    __shared__ float xs[32 * K];
    int n0 = blockIdx.x * 32;
    int tid = threadIdx.x;   // 0..191
    for (int t = tid; t < 32 * K; t += 192) {
        int i = t / K, k = t - i * K;
        int n = n0 + i;
        xs[t] = (n < NN) ? x[n * K + k] : 0.f;
    }
    __syncthreads();
    float acc[32];
#pragma unroll
    for (int i = 0; i < 32; i++) acc[i] = 0.f;
    int j = tid;
    for (int k = 0; k < K; k++) {
        float wk = W[k * HC + j];
#pragma unroll
        for (int i = 0; i < 32; i++) acc[i] += xs[i * K + k] * wk;
    }
    int rem = NN - n0;
#pragma unroll
    for (int i = 0; i < 32; i++)
        if (i < rem) out[(n0 + i) * HC + j] = acc[i];

    // fused attdot: per wave (= head h), reduce acc[i]*w over 64 lanes
    int h = tid >> 6, c = tid & 63;
    float wa = asrcw[h * 64 + c], wd = adstw[h * 64 + c];
    for (int i = 0; i < 32; i++) {
        if (i >= rem) break;
        float p = acc[i] * wa;
        float q = acc[i] * wd;
#pragma unroll
        for (int off = 32; off; off >>= 1) {
            p += __shfl_xor(p, off, 64);
            q += __shfl_xor(q, off, 64);
        }
        if (c == 0) {
            asrc[(n0 + i) * 3 + h] = p;
            adst[(n0 + i) * 3 + h] = q;
        }
    }
}

// ---------------- alpha (leaky relu) in PACKED (CSR) order, streaming ----------------
__global__ void k_alphaP(const int* __restrict__ srcP, const int* __restrict__ dstP,
                         const float* __restrict__ eaP, const float* __restrict__ asrc,
                         const float* __restrict__ adst, const float* __restrict__ wedot,
                         int woff, float* __restrict__ alphaP) {
    int p = blockIdx.x * 256 + threadIdx.x;
    if (p >= TOTAL) return;
    int s = srcP[p], d = dstP[p];
    float ea = eaP[p];
#pragma unroll
    for (int h = 0; h < 3; h++) {
        float a = asrc[s * 3 + h] + adst[d * 3 + h] + ea * wedot[woff + h];
        alphaP[p * 3 + h] = (a > 0.f) ? a : 0.2f * a;
    }
}

// ---------------- fused segment softmax + aggregation (per node) ----------------
// alphaP holds alpha on entry; holds UNNORMALIZED e on exit. rdenom[n*3+h] = 1/(sum+eps).
__global__ void k_gatherSM(const u32* __restrict__ startv, const int* __restrict__ deg,
                           const int* __restrict__ srcP, float* __restrict__ alphaP,
                           const float* __restrict__ xh, const float* __restrict__ bias,
                           float* __restrict__ rdenom, float* __restrict__ hout) {
    int n = blockIdx.x;
    int j = threadIdx.x;      // 0..191
    int h = j >> 6;
    u32 st = startv[n];
    int L = deg[n] + 1;
    const float* ap = alphaP + (size_t)st * 3 + h;
    const int* sp = srcP + st;

    // pass 1: max (sequential reads, broadcast within wave)
    float m = -1e30f;
    int p = 0;
    for (; p + 4 <= L; p += 4) {
        float a0 = ap[3 * p], a1 = ap[3 * p + 3], a2 = ap[3 * p + 6], a3 = ap[3 * p + 9];
        m = fmaxf(m, fmaxf(fmaxf(a0, a1), fmaxf(a2, a3)));
    }
    for (; p < L; p++) m = fmaxf(m, ap[3 * p]);

    // pass 2: e = exp(a-m), acc += e * xh[src], sum e; write e back (lane c==0 of each wave)
    float acc = 0.f, ssum = 0.f;
    int c = j & 63;
    p = 0;
    for (; p + 4 <= L; p += 4) {
        int s0 = sp[p], s1 = sp[p + 1], s2 = sp[p + 2], s3 = sp[p + 3];
        float e0 = __expf(ap[3 * p] - m);
        float e1 = __expf(ap[3 * p + 3] - m);
        float e2 = __expf(ap[3 * p + 6] - m);
        float e3 = __expf(ap[3 * p + 9] - m);
        float x0 = xh[(size_t)s0 * HC + j];
        float x1 = xh[(size_t)s1 * HC + j];
        float x2 = xh[(size_t)s2 * HC + j];
        float x3 = xh[(size_t)s3 * HC + j];
        if (c == 0) {
            alphaP[(size_t)(st + p) * 3 + h] = e0;
            alphaP[(size_t)(st + p + 1) * 3 + h] = e1;
            alphaP[(size_t)(st + p + 2) * 3 + h] = e2;
            alphaP[(size_t)(st + p + 3) * 3 + h] = e3;
        }
        acc += e0 * x0;
        acc += e1 * x1;
        acc += e2 * x2;
        acc += e3 * x3;
        ssum += (e0 + e1) + (e2 + e3);
    }
    for (; p < L; p++) {
        int s0 = sp[p];
        float e0 = __expf(ap[3 * p] - m);
        float x0 = xh[(size_t)s0 * HC + j];
        if (c == 0) alphaP[(size_t)(st + p) * 3 + h] = e0;
        acc += e0 * x0;
        ssum += e0;
    }
    float r = 1.f / (ssum + 1e-16f);
    if (c == 0) rdenom[n * 3 + h] = r;
    float o = acc * r + bias[j];
    hout[(size_t)n * HC + j] = (o > 0.f) ? o : expm1f(o);
}

// ---------------- normalized attn in original entry order ----------------
__global__ void k_attnout(const u32* __restrict__ posOf, const int* __restrict__ ei,
                          const float* __restrict__ eP, const float* __restrict__ rdenom,
                          float* __restrict__ attn) {
    int i = blockIdx.x * 256 + threadIdx.x;
    if (i >= TOTAL) return;
    u32 pos = posOf[i];
    int d = (i < EE) ? ei[EE + i] : (i - EE);
#pragma unroll
    for (int h = 0; h < 3; h++)
        attn[(size_t)i * 3 + h] = eP[(size_t)pos * 3 + h] * rdenom[d * 3 + h];
}

// ---------------- pooling ----------------
__global__ void k_poolinit(u32* __restrict__ pmax) {
    int i = blockIdx.x * 256 + threadIdx.x;
    if (i < GG * HC) pmax[i] = 0x007FFFFFu;   // fmap(-inf)
}

__global__ void k_pool(const float* __restrict__ h2, const int* __restrict__ batch,
                       float* __restrict__ psum, u32* __restrict__ pmax,
                       int* __restrict__ pcnt) {
    const int CH = 256;
    int n0 = blockIdx.x * CH;
    if (n0 >= NN) return;
    int j = threadIdx.x;
    int nend = min(NN, n0 + CH);
    int curg = batch[n0];
    float sum = 0.f, mx = -1e30f;
    int c = 0;
    for (int n = n0; n < nend; n++) {
        int g = batch[n];
        if (g != curg) {
            atomicAdd(&psum[curg * HC + j], sum);
            atomicMax(&pmax[curg * HC + j], fmap(mx));
            if (j == 0) atomicAdd(&pcnt[curg], c);
            sum = 0.f; mx = -1e30f; c = 0; curg = g;
        }
        float v = h2[(size_t)n * HC + j];
        sum += v;
        mx = fmaxf(mx, v);
        c++;
    }
    atomicAdd(&psum[curg * HC + j], sum);
    atomicMax(&pmax[curg * HC + j], fmap(mx));
    if (j == 0) atomicAdd(&pcnt[curg], c);
}

// ---------------- head MLP ----------------
__global__ void k_head(const float* __restrict__ psum, const u32* __restrict__ pmax,
                       const int* __restrict__ pcnt, const float* __restrict__ fc1w,
                       const float* __restrict__ fc1b, const float* __restrict__ fc2w,
                       const float* __restrict__ fc2b, float* __restrict__ logits) {
    __shared__ float z[2 * HC];
    int g = blockIdx.x;
    int t = threadIdx.x;   // 0..63
    float cnt = fmaxf((float)pcnt[g], 1.f);
    for (int k = t; k < 2 * HC; k += 64)
        z[k] = (k < HC) ? psum[g * HC + k] / cnt : funmap(pmax[g * HC + (k - HC)]);
    __syncthreads();
    float acc = fc1b[t];
    for (int k = 0; k < 2 * HC; k++) acc += z[k] * fc1w[k * 64 + t];
    acc = fmaxf(acc, 0.f);
    float v = acc * fc2w[t];
#pragma unroll
    for (int off = 32; off; off >>= 1) v += __shfl_xor(v, off, 64);
    if (t == 0) logits[g] = v + fc2b[0];
}

// ---------------- launcher ----------------
extern "C" void kernel_launch(void* const* d_in, const int* in_sizes, int n_in,
                              void* d_out, int out_size, void* d_ws, size_t ws_size,
                              hipStream_t stream) {
    const float* x     = (const float*)d_in[0];
    const float* eattr = (const float*)d_in[1];
    const float* W1    = (const float*)d_in[2];
    const float* as1   = (const float*)d_in[3];
    const float* ad1   = (const float*)d_in[4];
    const float* We1   = (const float*)d_in[5];
    const float* ae1   = (const float*)d_in[6];
    const float* b1    = (const float*)d_in[7];
    const float* W2    = (const float*)d_in[8];
    const float* as2   = (const float*)d_in[9];
    const float* ad2   = (const float*)d_in[10];
    const float* We2   = (const float*)d_in[11];
    const float* ae2   = (const float*)d_in[12];
    const float* b2    = (const float*)d_in[13];
    const float* fc1w  = (const float*)d_in[14];
    const float* fc1b  = (const float*)d_in[15];
    const float* fc2w  = (const float*)d_in[16];
    const float* fc2b  = (const float*)d_in[17];
    const int* ei      = (const int*)d_in[18];
    const int* batch   = (const int*)d_in[19];

    float* logits = (float*)d_out;
    float* attn1  = logits + GG;
    float* attn2  = attn1 + (size_t)TOTAL * 3;

    // workspace layout
    float* bufA    = (float*)d_ws;                   // N*192  (xh)
    float* bufB    = bufA + (size_t)NN * HC;         // N*192  (h)
    float* alphaP  = bufB + (size_t)NN * HC;         // TOTAL*3 (alpha -> e)
    int*   srcP    = (int*)(alphaP + (size_t)TOTAL * 3);
    int*   dstP    = srcP + TOTAL;
    float* eaP     = (float*)(dstP + TOTAL);
    u32*   posOf   = (u32*)(eaP + TOTAL);
    int*   deg     = (int*)(posOf + TOTAL);
    float* attrsum = (float*)(deg + NN);
    float* asrc    = attrsum + NN;                   // N*3
    float* adst    = asrc + NN * 3;                  // N*3
    float* rdenom  = adst + NN * 3;                  // N*3
    u32*   startv  = (u32*)(rdenom + NN * 3);        // N
    u32*   cursor  = startv + NN;                    // N
    u32*   blocksum= cursor + NN;                    // 64
    float* wedot   = (float*)(blocksum + 64);        // 8
    float* psum    = wedot + 8;                      // G*192
    u32*   pmax    = (u32*)(psum + GG * HC);         // G*192
    int*   pcnt    = (int*)(pmax + GG * HC);         // G

    // zero init
    hipMemsetAsync(deg, 0, NN * sizeof(int), stream);
    hipMemsetAsync(attrsum, 0, NN * sizeof(float), stream);
    hipMemsetAsync(psum, 0, GG * HC * sizeof(float), stream);
    hipMemsetAsync(pcnt, 0, GG * sizeof(int), stream);

    // graph structure (shared by both layers)
    k_deg<<<(EE + 255) / 256, 256, 0, stream>>>(ei, eattr, deg, attrsum);
    k_scan1<<<49, 1024, 0, stream>>>(deg, startv, blocksum);
    k_scan2<<<1, 64, 0, stream>>>(blocksum, 49);
    k_scan3<<<(NN + 255) / 256, 256, 0, stream>>>(startv, blocksum, cursor);
    k_fill<<<(TOTAL + 255) / 256, 256, 0, stream>>>(ei, eattr, attrsum, deg, cursor,
                                                    srcP, dstP, eaP, posOf);
    k_wedot<<<1, 384, 0, stream>>>(We1, ae1, We2, ae2, wedot);
    k_poolinit<<<(GG * HC + 255) / 256, 256, 0, stream>>>(pmax);

    const int NB = (NN + 31) / 32;

    // ---- layer 1 ----
    k_gemm<IN_DIM><<<NB, 192, 0, stream>>>(x, W1, as1, ad1, bufA, asrc, adst);
    k_alphaP<<<(TOTAL + 255) / 256, 256, 0, stream>>>(srcP, dstP, eaP, asrc, adst,
                                                      wedot, 0, alphaP);
    k_gatherSM<<<NN, 192, 0, stream>>>(startv, deg, srcP, alphaP, bufA, b1, rdenom, bufB);
    k_attnout<<<(TOTAL + 255) / 256, 256, 0, stream>>>(posOf, ei, alphaP, rdenom, attn1);

    // ---- layer 2 ----
    k_gemm<HC><<<NB, 192, 0, stream>>>(bufB, W2, as2, ad2, bufA, asrc, adst);
    k_alphaP<<<(TOTAL + 255) / 256, 256, 0, stream>>>(srcP, dstP, eaP, asrc, adst,
                                                      wedot, 3, alphaP);
    k_gatherSM<<<NN, 192, 0, stream>>>(startv, deg, srcP, alphaP, bufA, b2, rdenom, bufB);
    k_attnout<<<(TOTAL + 255) / 256, 256, 0, stream>>>(posOf, ei, alphaP, rdenom, attn2);

    // ---- pooling + head ----
    k_pool<<<(NN + 255) / 256, 192, 0, stream>>>(bufB, batch, psum, pmax, pcnt);
    k_head<<<GG, 64, 0, stream>>>(psum, pmax, pcnt, fc1w, fc1b, fc2w, fc2b, logits);
}

// Round 3
// 772.001 us; speedup vs baseline: 1.5624x; 1.1778x over previous
//
#include <hip/hip_runtime.h>
#include <hip/hip_bf16.h>

typedef unsigned int u32;
typedef __attribute__((ext_vector_type(8))) short short8;
typedef __attribute__((ext_vector_type(4))) float f32x4;

#define NN 50000
#define NPAD 50048       // padded to 64-row multiple for MFMA blocks
#define EE 800000
#define GG 64
#define HH 3
#define CC 64
#define IN_DIM 75
#define KP1 96           // padded K for layer-1 GEMM
#define HC 192           // H*C
#define TOTAL (EE + NN)  // edge entries incl self loops

// ---------------- helpers ----------------
__device__ __forceinline__ u32 fmap(float f) {
    u32 u = __float_as_uint(f);
    return (u & 0x80000000u) ? ~u : (u | 0x80000000u);
}
__device__ __forceinline__ float funmap(u32 m) {
    u32 u = (m & 0x80000000u) ? (m ^ 0x80000000u) : ~m;
    return __uint_as_float(u);
}

// ---------------- degree + edge-attr sum ----------------
__global__ void k_deg(const int* __restrict__ ei, const float* __restrict__ eattr,
                      int* __restrict__ deg, float* __restrict__ attrsum) {
    int e = blockIdx.x * 256 + threadIdx.x;
    if (e >= EE) return;
    int d = ei[EE + e];
    atomicAdd(&deg[d], 1);
    atomicAdd(&attrsum[d], eattr[e]);
}

// ---------------- prefix scan (deg+1) : 2-level ----------------
__global__ void k_scan1(const int* __restrict__ deg, u32* __restrict__ startv,
                        u32* __restrict__ blocksum) {
    __shared__ u32 sh[1024];
    int t = threadIdx.x;
    int n = blockIdx.x * 1024 + t;
    u32 v = (n < NN) ? (u32)(deg[n] + 1) : 0u;
    u32 val = v;
    sh[t] = val;
    __syncthreads();
    for (int off = 1; off < 1024; off <<= 1) {
        u32 y = (t >= off) ? sh[t - off] : 0u;
        __syncthreads();
        val += y;
        sh[t] = val;
        __syncthreads();
    }
    if (n < NN) startv[n] = val - v;   // block-exclusive
    if (t == 0) blocksum[blockIdx.x] = sh[1023];
}

__global__ void k_scan2(u32* __restrict__ blocksum, int nb) {
    if (threadIdx.x == 0) {
        u32 acc = 0;
        for (int b = 0; b < nb; b++) { u32 t = blocksum[b]; blocksum[b] = acc; acc += t; }
    }
}

__global__ void k_scan3(u32* __restrict__ startv, const u32* __restrict__ blocksum,
                        u32* __restrict__ cursor) {
    int n = blockIdx.x * 256 + threadIdx.x;
    if (n >= NN) return;
    u32 s = startv[n] + blocksum[n >> 10];
    startv[n] = s;
    cursor[n] = s;
}

// fill CSR-ordered streams: srcP/dstP/eaP packed by destination segment; posOf maps entry->pos
__global__ void k_fill(const int* __restrict__ ei, const float* __restrict__ eattr,
                       const float* __restrict__ attrsum, const int* __restrict__ deg,
                       u32* __restrict__ cursor, int* __restrict__ srcP,
                       int* __restrict__ dstP, float* __restrict__ eaP,
                       u32* __restrict__ posOf) {
    int i = blockIdx.x * 256 + threadIdx.x;
    if (i >= TOTAL) return;
    int s, d;
    float ea;
    if (i < EE) {
        s = ei[i]; d = ei[EE + i]; ea = eattr[i];
    } else {
        s = d = i - EE;
        ea = attrsum[s] / fmaxf((float)deg[s], 1.f);
    }
    u32 pos = atomicAdd(&cursor[d], 1u);
    srcP[pos] = s;
    dstP[pos] = d;
    eaP[pos] = ea;
    posOf[i] = pos;
}

// ---------------- per-head scalar: dot(We_col_h, a_e_h) for both layers ----------------
__global__ void k_wedot(const float* __restrict__ We1, const float* __restrict__ ae1,
                        const float* __restrict__ We2, const float* __restrict__ ae2,
                        float* __restrict__ wedot) {
    int w = threadIdx.x >> 6;      // 0..5
    int c = threadIdx.x & 63;
    int layer = w / 3, h = w % 3;
    const float* We = layer ? We2 : We1;
    const float* ae = layer ? ae2 : ae1;
    float v = We[h * 64 + c] * ae[h * 64 + c];
#pragma unroll
    for (int off = 32; off; off >>= 1) v += __shfl_xor(v, off, 64);
    if (c == 0) wedot[layer * 3 + h] = v;
}

// ---------------- input conversions for MFMA ----------------
// xb[NPAD][KP1] bf16, zero-padded rows and k>=IN_DIM
__global__ void k_xconv(const float* __restrict__ x, __hip_bfloat16* __restrict__ xb) {
    int i = blockIdx.x * 256 + threadIdx.x;
    if (i >= NPAD * KP1) return;
    int n = i / KP1, k = i - n * KP1;
    float v = (n < NN && k < IN_DIM) ? x[n * IN_DIM + k] : 0.f;
    xb[i] = __float2bfloat16(v);
}

// Wt1[192][KP1], Wt2[192][192]   (transposed: Wt[j][k] = W[k][j])
__global__ void k_wtconv(const float* __restrict__ W1, const float* __restrict__ W2,
                         __hip_bfloat16* __restrict__ Wt1, __hip_bfloat16* __restrict__ Wt2) {
    int i = blockIdx.x * 256 + threadIdx.x;
    if (i < HC * KP1) {
        int j = i / KP1, k = i - j * KP1;
        Wt1[i] = __float2bfloat16(k < IN_DIM ? W1[k * HC + j] : 0.f);
    }
    if (i < HC * HC) {
        int j = i / HC, k = i - j * HC;
        Wt2[i] = __float2bfloat16(W2[k * HC + j]);
    }
}

// ---------------- MFMA GEMM: out[NPAD,192] = A[NPAD,KPAD] @ Wt^T ----------------
// A row-major bf16 [NPAD][KPAD]; Wt row-major bf16 [192][KPAD] (Wt[j][k]=W[k][j]).
// Block: 256 thr = 4 waves; 64 rows x 192 cols per block; 12 col-frags per wave.
template <int KPAD>
__global__ __launch_bounds__(256) void k_mfma_gemm(const __hip_bfloat16* __restrict__ A,
                                                   const __hip_bfloat16* __restrict__ Wt,
                                                   float* __restrict__ out) {
    int wid = threadIdx.x >> 6;
    int lane = threadIdx.x & 63;
    int r0 = blockIdx.x * 64 + wid * 16;
    int lr = lane & 15;     // A: row-in-16, B: col-in-16
    int g = lane >> 4;      // k-subgroup (8 elems each)
    const short* Ab = (const short*)A;
    const short* Wb = (const short*)Wt;
    f32x4 acc[12];
#pragma unroll
    for (int f = 0; f < 12; f++) acc[f] = (f32x4){0.f, 0.f, 0.f, 0.f};
#pragma unroll
    for (int k0 = 0; k0 < KPAD; k0 += 32) {
        short8 a = *(const short8*)(Ab + (size_t)(r0 + lr) * KPAD + k0 + 8 * g);
#pragma unroll
        for (int f = 0; f < 12; f++) {
            short8 b = *(const short8*)(Wb + (size_t)(f * 16 + lr) * KPAD + k0 + 8 * g);
            acc[f] = __builtin_amdgcn_mfma_f32_16x16x32_bf16(a, b, acc[f], 0, 0, 0);
        }
    }
    int rbase = r0 + 4 * g;   // D: col = lane&15, row = 4*(lane>>4)+reg
#pragma unroll
    for (int f = 0; f < 12; f++) {
        int col = f * 16 + lr;
#pragma unroll
        for (int r = 0; r < 4; r++) {
            int row = rbase + r;
            if (row < NN) out[(size_t)row * HC + col] = acc[f][r];
        }
    }
}

// ---------------- per-node attention dots ----------------
__global__ void k_attdot(const float* __restrict__ xh, const float* __restrict__ asrcw,
                         const float* __restrict__ adstw, float* __restrict__ asrc,
                         float* __restrict__ adst) {
    int n = blockIdx.x;
    int h = threadIdx.x >> 6, c = threadIdx.x & 63;
    float v = xh[(size_t)n * HC + h * 64 + c];
    float p = v * asrcw[h * 64 + c];
    float q = v * adstw[h * 64 + c];
#pragma unroll
    for (int off = 32; off; off >>= 1) {
        p += __shfl_xor(p, off, 64);
        q += __shfl_xor(q, off, 64);
    }
    if (c == 0) { asrc[n * 3 + h] = p; adst[n * 3 + h] = q; }
}

// ---------------- alpha (leaky relu) in PACKED (CSR) order, streaming ----------------
__global__ void k_alphaP(const int* __restrict__ srcP, const int* __restrict__ dstP,
                         const float* __restrict__ eaP, const float* __restrict__ asrc,
                         const float* __restrict__ adst, const float* __restrict__ wedot,
                         int woff, float* __restrict__ alphaP) {
    int p = blockIdx.x * 256 + threadIdx.x;
    if (p >= TOTAL) return;
    int s = srcP[p], d = dstP[p];
    float ea = eaP[p];
#pragma unroll
    for (int h = 0; h < 3; h++) {
        float a = asrc[s * 3 + h] + adst[d * 3 + h] + ea * wedot[woff + h];
        alphaP[(size_t)p * 3 + h] = (a > 0.f) ? a : 0.2f * a;
    }
}

// ---------------- fused segment softmax + aggregation (per node) ----------------
// alphaP holds alpha on entry; holds UNNORMALIZED e on exit. rdenom[n*3+h] = 1/(sum+eps).
// OUT_BF16=1: write bf16 (feeds next GEMM); else f32.
template <int OUT_BF16>
__global__ void k_gatherSM(const u32* __restrict__ startv, const int* __restrict__ deg,
                           const int* __restrict__ srcP, float* __restrict__ alphaP,
                           const float* __restrict__ xh, const float* __restrict__ bias,
                           float* __restrict__ rdenom, float* __restrict__ hout,
                           __hip_bfloat16* __restrict__ hb) {
    int n = blockIdx.x;
    int j = threadIdx.x;      // 0..191
    int h = j >> 6;
    u32 st = startv[n];
    int L = deg[n] + 1;
    const float* ap = alphaP + (size_t)st * 3 + h;
    const int* sp = srcP + st;

    // pass 1: max (sequential reads, broadcast within wave)
    float m = -1e30f;
    int p = 0;
    for (; p + 4 <= L; p += 4) {
        float a0 = ap[3 * p], a1 = ap[3 * p + 3], a2 = ap[3 * p + 6], a3 = ap[3 * p + 9];
        m = fmaxf(m, fmaxf(fmaxf(a0, a1), fmaxf(a2, a3)));
    }
    for (; p < L; p++) m = fmaxf(m, ap[3 * p]);

    // pass 2: e = exp(a-m), acc += e * xh[src], sum e; write e back (lane c==0 of each wave)
    float acc = 0.f, ssum = 0.f;
    int c = j & 63;
    p = 0;
    for (; p + 4 <= L; p += 4) {
        int s0 = sp[p], s1 = sp[p + 1], s2 = sp[p + 2], s3 = sp[p + 3];
        float e0 = __expf(ap[3 * p] - m);
        float e1 = __expf(ap[3 * p + 3] - m);
        float e2 = __expf(ap[3 * p + 6] - m);
        float e3 = __expf(ap[3 * p + 9] - m);
        float x0 = xh[(size_t)s0 * HC + j];
        float x1 = xh[(size_t)s1 * HC + j];
        float x2 = xh[(size_t)s2 * HC + j];
        float x3 = xh[(size_t)s3 * HC + j];
        if (c == 0) {
            alphaP[(size_t)(st + p) * 3 + h] = e0;
            alphaP[(size_t)(st + p + 1) * 3 + h] = e1;
            alphaP[(size_t)(st + p + 2) * 3 + h] = e2;
            alphaP[(size_t)(st + p + 3) * 3 + h] = e3;
        }
        acc += e0 * x0;
        acc += e1 * x1;
        acc += e2 * x2;
        acc += e3 * x3;
        ssum += (e0 + e1) + (e2 + e3);
    }
    for (; p < L; p++) {
        int s0 = sp[p];
        float e0 = __expf(ap[3 * p] - m);
        float x0 = xh[(size_t)s0 * HC + j];
        if (c == 0) alphaP[(size_t)(st + p) * 3 + h] = e0;
        acc += e0 * x0;
        ssum += e0;
    }
    float r = 1.f / (ssum + 1e-16f);
    if (c == 0) rdenom[n * 3 + h] = r;
    float o = acc * r + bias[j];
    o = (o > 0.f) ? o : expm1f(o);
    if (OUT_BF16) hb[(size_t)n * HC + j] = __float2bfloat16(o);
    else hout[(size_t)n * HC + j] = o;
}

// ---------------- normalized attn in original entry order ----------------
__global__ void k_attnout(const u32* __restrict__ posOf, const int* __restrict__ ei,
                          const float* __restrict__ eP, const float* __restrict__ rdenom,
                          float* __restrict__ attn) {
    int i = blockIdx.x * 256 + threadIdx.x;
    if (i >= TOTAL) return;
    u32 pos = posOf[i];
    int d = (i < EE) ? ei[EE + i] : (i - EE);
#pragma unroll
    for (int h = 0; h < 3; h++)
        attn[(size_t)i * 3 + h] = eP[(size_t)pos * 3 + h] * rdenom[d * 3 + h];
}

// ---------------- pooling ----------------
__global__ void k_poolinit(u32* __restrict__ pmax) {
    int i = blockIdx.x * 256 + threadIdx.x;
    if (i < GG * HC) pmax[i] = 0x007FFFFFu;   // fmap(-inf)
}

__global__ void k_pool(const float* __restrict__ h2, const int* __restrict__ batch,
                       float* __restrict__ psum, u32* __restrict__ pmax,
                       int* __restrict__ pcnt) {
    const int CH = 256;
    int n0 = blockIdx.x * CH;
    if (n0 >= NN) return;
    int j = threadIdx.x;
    int nend = min(NN, n0 + CH);
    int curg = batch[n0];
    float sum = 0.f, mx = -1e30f;
    int c = 0;
    for (int n = n0; n < nend; n++) {
        int g = batch[n];
        if (g != curg) {
            atomicAdd(&psum[curg * HC + j], sum);
            atomicMax(&pmax[curg * HC + j], fmap(mx));
            if (j == 0) atomicAdd(&pcnt[curg], c);
            sum = 0.f; mx = -1e30f; c = 0; curg = g;
        }
        float v = h2[(size_t)n * HC + j];
        sum += v;
        mx = fmaxf(mx, v);
        c++;
    }
    atomicAdd(&psum[curg * HC + j], sum);
    atomicMax(&pmax[curg * HC + j], fmap(mx));
    if (j == 0) atomicAdd(&pcnt[curg], c);
}

// ---------------- head MLP ----------------
__global__ void k_head(const float* __restrict__ psum, const u32* __restrict__ pmax,
                       const int* __restrict__ pcnt, const float* __restrict__ fc1w,
                       const float* __restrict__ fc1b, const float* __restrict__ fc2w,
                       const float* __restrict__ fc2b, float* __restrict__ logits) {
    __shared__ float z[2 * HC];
    int g = blockIdx.x;
    int t = threadIdx.x;   // 0..63
    float cnt = fmaxf((float)pcnt[g], 1.f);
    for (int k = t; k < 2 * HC; k += 64)
        z[k] = (k < HC) ? psum[g * HC + k] / cnt : funmap(pmax[g * HC + (k - HC)]);
    __syncthreads();
    float acc = fc1b[t];
    for (int k = 0; k < 2 * HC; k++) acc += z[k] * fc1w[k * 64 + t];
    acc = fmaxf(acc, 0.f);
    float v = acc * fc2w[t];
#pragma unroll
    for (int off = 32; off; off >>= 1) v += __shfl_xor(v, off, 64);
    if (t == 0) logits[g] = v + fc2b[0];
}

// ---------------- launcher ----------------
extern "C" void kernel_launch(void* const* d_in, const int* in_sizes, int n_in,
                              void* d_out, int out_size, void* d_ws, size_t ws_size,
                              hipStream_t stream) {
    const float* x     = (const float*)d_in[0];
    const float* eattr = (const float*)d_in[1];
    const float* W1    = (const float*)d_in[2];
    const float* as1   = (const float*)d_in[3];
    const float* ad1   = (const float*)d_in[4];
    const float* We1   = (const float*)d_in[5];
    const float* ae1   = (const float*)d_in[6];
    const float* b1    = (const float*)d_in[7];
    const float* W2    = (const float*)d_in[8];
    const float* as2   = (const float*)d_in[9];
    const float* ad2   = (const float*)d_in[10];
    const float* We2   = (const float*)d_in[11];
    const float* ae2   = (const float*)d_in[12];
    const float* b2    = (const float*)d_in[13];
    const float* fc1w  = (const float*)d_in[14];
    const float* fc1b  = (const float*)d_in[15];
    const float* fc2w  = (const float*)d_in[16];
    const float* fc2b  = (const float*)d_in[17];
    const int* ei      = (const int*)d_in[18];
    const int* batch   = (const int*)d_in[19];

    float* logits = (float*)d_out;
    float* attn1  = logits + GG;
    float* attn2  = attn1 + (size_t)TOTAL * 3;

    // workspace layout
    float* bufA    = (float*)d_ws;                   // NN*192  (xh, f32)
    float* bufB    = bufA + (size_t)NN * HC;         // NN*192  (h2, f32)
    float* alphaP  = bufB + (size_t)NN * HC;         // TOTAL*3 (alpha -> e)
    int*   srcP    = (int*)(alphaP + (size_t)TOTAL * 3);
    int*   dstP    = srcP + TOTAL;
    float* eaP     = (float*)(dstP + TOTAL);
    u32*   posOf   = (u32*)(eaP + TOTAL);
    int*   deg     = (int*)(posOf + TOTAL);
    float* attrsum = (float*)(deg + NN);
    float* asrc    = attrsum + NN;                   // N*3
    float* adst    = asrc + NN * 3;                  // N*3
    float* rdenom  = adst + NN * 3;                  // N*3
    u32*   startv  = (u32*)(rdenom + NN * 3);        // N
    u32*   cursor  = startv + NN;                    // N
    u32*   blocksum= cursor + NN;                    // 64
    float* wedot   = (float*)(blocksum + 64);        // 8
    float* psum    = wedot + 8;                      // G*192
    u32*   pmax    = (u32*)(psum + GG * HC);         // G*192
    int*   pcnt    = (int*)(pmax + GG * HC);         // G
    __hip_bfloat16* xb  = (__hip_bfloat16*)(pcnt + 64);        // NPAD*KP1
    __hip_bfloat16* hb  = xb + (size_t)NPAD * KP1;             // NPAD*192
    __hip_bfloat16* Wt1 = hb + (size_t)NPAD * HC;              // 192*KP1
    __hip_bfloat16* Wt2 = Wt1 + (size_t)HC * KP1;              // 192*192

    // zero init
    hipMemsetAsync(deg, 0, NN * sizeof(int), stream);
    hipMemsetAsync(attrsum, 0, NN * sizeof(float), stream);
    hipMemsetAsync(psum, 0, GG * HC * sizeof(float), stream);
    hipMemsetAsync(pcnt, 0, GG * sizeof(int), stream);
    hipMemsetAsync(hb + (size_t)NN * HC, 0, (size_t)(NPAD - NN) * HC * sizeof(__hip_bfloat16), stream);

    // graph structure (shared by both layers) + weight prep
    k_deg<<<(EE + 255) / 256, 256, 0, stream>>>(ei, eattr, deg, attrsum);
    k_scan1<<<49, 1024, 0, stream>>>(deg, startv, blocksum);
    k_scan2<<<1, 64, 0, stream>>>(blocksum, 49);
    k_scan3<<<(NN + 255) / 256, 256, 0, stream>>>(startv, blocksum, cursor);
    k_fill<<<(TOTAL + 255) / 256, 256, 0, stream>>>(ei, eattr, attrsum, deg, cursor,
                                                    srcP, dstP, eaP, posOf);
    k_wedot<<<1, 384, 0, stream>>>(We1, ae1, We2, ae2, wedot);
    k_poolinit<<<(GG * HC + 255) / 256, 256, 0, stream>>>(pmax);
    k_xconv<<<(NPAD * KP1 + 255) / 256, 256, 0, stream>>>(x, xb);
    k_wtconv<<<(HC * HC + 255) / 256, 256, 0, stream>>>(W1, W2, Wt1, Wt2);

    const int GB = NPAD / 64;   // 782 MFMA blocks

    // ---- layer 1 ----
    k_mfma_gemm<KP1><<<GB, 256, 0, stream>>>(xb, Wt1, bufA);
    k_attdot<<<NN, 192, 0, stream>>>(bufA, as1, ad1, asrc, adst);
    k_alphaP<<<(TOTAL + 255) / 256, 256, 0, stream>>>(srcP, dstP, eaP, asrc, adst,
                                                      wedot, 0, alphaP);
    k_gatherSM<1><<<NN, 192, 0, stream>>>(startv, deg, srcP, alphaP, bufA, b1, rdenom,
                                          bufB, hb);
    k_attnout<<<(TOTAL + 255) / 256, 256, 0, stream>>>(posOf, ei, alphaP, rdenom, attn1);

    // ---- layer 2 ----
    k_mfma_gemm<HC><<<GB, 256, 0, stream>>>(hb, Wt2, bufA);
    k_attdot<<<NN, 192, 0, stream>>>(bufA, as2, ad2, asrc, adst);
    k_alphaP<<<(TOTAL + 255) / 256, 256, 0, stream>>>(srcP, dstP, eaP, asrc, adst,
                                                      wedot, 3, alphaP);
    k_gatherSM<0><<<NN, 192, 0, stream>>>(startv, deg, srcP, alphaP, bufA, b2, rdenom,
                                          bufB, hb);
    k_attnout<<<(TOTAL + 255) / 256, 256, 0, stream>>>(posOf, ei, alphaP, rdenom, attn2);

    // ---- pooling + head ----
    k_pool<<<(NN + 255) / 256, 192, 0, stream>>>(bufB, batch, psum, pmax, pcnt);
    k_head<<<GG, 64, 0, stream>>>(psum, pmax, pcnt, fc1w, fc1b, fc2w, fc2b, logits);
}